// Round 9
// baseline (722.123 us; speedup 1.0000x reference)
//
#include <hip/hip_runtime.h>

#define HID 256
#define SB  16      // samples per block (512 threads, 8 waves)

typedef float v2f __attribute__((ext_vector_type(2)));
typedef float v4f __attribute__((ext_vector_type(4)));
typedef int   i32x4 __attribute__((ext_vector_type(4)));
typedef int   i32x2 __attribute__((ext_vector_type(2)));

__device__ __forceinline__ float fast_tanh(float x) {
    float ax = __builtin_fabsf(x);
    float e  = __expf(2.0f * ax);
    float t  = 1.0f - 2.0f * __builtin_amdgcn_rcpf(e + 1.0f);
    return __builtin_copysignf(t, x);
}

__device__ __forceinline__ v2f pk_fma_lo(v2f a, v2f b, v2f c) {
    asm("v_pk_fma_f32 %0, %1, %2, %0 op_sel_hi:[1,0,1]" : "+v"(c) : "v"(a), "v"(b));
    return c;
}
__device__ __forceinline__ v2f pk_fma_hi(v2f a, v2f b, v2f c) {
    asm("v_pk_fma_f32 %0, %1, %2, %0 op_sel:[0,1,0] op_sel_hi:[1,1,1]" : "+v"(c) : "v"(a), "v"(b));
    return c;
}

__device__ __forceinline__ v2f red64(v2f v) {
#pragma unroll
    for (int m = 1; m < 64; m <<= 1) {
        v.x += __shfl_xor(v.x, m, 64);
        v.y += __shfl_xor(v.y, m, 64);
    }
    return v;
}

__device__ __forceinline__ float red_lq(float v) {
    v += __shfl_xor(v, 16, 64);
    v += __shfl_xor(v, 32, 64);
    return v;
}

__device__ __forceinline__ float hsum4(v4f v) { return (v.x + v.y) + (v.z + v.w); }

// exact 3-way bf16 split (RNE): x ~= h + m + l, residual <= 2^-25 |x|
__device__ __forceinline__ void split3(float x, unsigned short& h, unsigned short& m, unsigned short& l) {
    unsigned u0 = __float_as_uint(x);
    unsigned short hh = (unsigned short)((u0 + 0x7FFFu + ((u0 >> 16) & 1u)) >> 16);
    float r1 = x - __uint_as_float((unsigned)hh << 16);
    unsigned u1 = __float_as_uint(r1);
    unsigned short mm = (unsigned short)((u1 + 0x7FFFu + ((u1 >> 16) & 1u)) >> 16);
    float r2 = r1 - __uint_as_float((unsigned)mm << 16);
    unsigned u2 = __float_as_uint(r2);
    unsigned short ll = (unsigned short)((u2 + 0x7FFFu + ((u2 >> 16) & 1u)) >> 16);
    h = hh; m = mm; l = ll;
}

// Chained-accumulate MFMA (D += A*B in the MFMA C path). MFMA->MFMA same-dest
// chaining needs no waits; first use after VALU zero-init is separated by loads.
__device__ __forceinline__ void mfma_acc(v4f& d, i32x4 a, i32x4 b) {
    asm("v_mfma_f32_16x16x32_bf16 %0, %1, %2, %0" : "+v"(d) : "v"(a), "v"(b));
}

// Hazard-safe zero-C MFMA whose result is immediately VALU-readable: the s_nops
// live INSIDE the asm blob so no compiler scheduling can shrink the distance.
// s_nop 1 covers VALU(zero-init)->MFMA SrcC read; s_nop 7+3 (12 states) covers
// MFMA->VALU read of D (4-pass XDL needs ~6).
__device__ __forceinline__ v4f mfma_safe(i32x4 a, i32x4 b) {
    v4f d = (v4f){0.0f, 0.0f, 0.0f, 0.0f};
    asm("s_nop 1\n\tv_mfma_f32_16x16x32_bf16 %0, %1, %2, %0\n\ts_nop 7\n\ts_nop 3"
        : "+v"(d) : "v"(a), "v"(b));
    return d;
}

// Standalone wait barrier before VALU-reading long-chained MFMA accumulators.
__device__ __forceinline__ void mfma_read_fence() {
    asm volatile("s_nop 7\n\ts_nop 3" ::: "memory");
}

// LDS byte offsets with FULL-granule XOR swizzle (bank-conflict fix, R9).
// Rows are 256B (X1) / 512B (X2) apart == bank-aliased; XOR the 16B-granule
// index with the full row index so any 16-lane row-slice hits 16 distinct
// granules. Bijective in kb16 per row -> same function for writes and reads.
// X1: 64 rows x 256B (16 granules); X2: 32 rows x 512B (32 granules). Plane = 16KB.
__device__ __forceinline__ int x1_off(int p, int j, int kb16) {
    int g = (kb16 ^ (j & 15) ^ ((j >> 4) << 2)) & 15;
    return p * 16384 + j * 256 + (g << 4);
}
__device__ __forceinline__ int x2_off(int p, int j2, int kb16) {
    int g = (kb16 ^ (j2 & 15) ^ ((j2 >> 4) << 3)) & 31;
    return p * 16384 + j2 * 512 + (g << 4);
}

#define ACC4(DST, SRC) \
    DST[0] = pk_fma_lo(SRC, wlo, DST[0]); \
    DST[1] = pk_fma_hi(SRC, wlo, DST[1]); \
    DST[2] = pk_fma_lo(SRC, whi, DST[2]); \
    DST[3] = pk_fma_hi(SRC, whi, DST[3]);

// ============================================================================
// pre-kernel: split LW2 into 6 fragment-ordered bf16 planes (d_ws).
// tensor 0 (GEMM1 A): A1[n][k] = LW2[k][n]; tensor 1 (GEMM2 A): A2[k][n] row-major.
// frag: pos = (Mt*8 + ks)*64 + lane, elem = A[Mt*16+(lane&15)][ks*32+(lane>>4)*8+i]
// ============================================================================
__global__ void build_planes(const float* __restrict__ LW2, unsigned short* __restrict__ P) {
    int t = blockIdx.x * 256 + threadIdx.x;   // 0..16383
    int tensor = t >> 13;
    int pos = t & 8191;
    int l = pos & 63, ks = (pos >> 6) & 7, Mt = pos >> 9;
    int mrow = Mt * 16 + (l & 15);
    int kb = ks * 32 + ((l >> 4) << 3);
    unsigned short sh[3][8];
#pragma unroll
    for (int i = 0; i < 8; ++i) {
        float v = tensor ? LW2[mrow * HID + kb + i] : LW2[(kb + i) * HID + mrow];
        split3(v, sh[0][i], sh[1][i], sh[2][i]);
    }
#pragma unroll
    for (int p = 0; p < 3; ++p) {
        unsigned short* dst = P + (tensor * 3 + p) * 65536 + pos * 8;
#pragma unroll
        for (int i = 0; i < 8; ++i) dst[i] = sh[p][i];
    }
}

// ============================================================================
// main MFMA kernel: 512 threads, 8 waves, SB=16, wave owns 2 M-tiles.
// Precision: per K-step the dominant Ah*Bh goes through mfma_safe (chain 1) and
// is folded into acc by a VALU RNE add; the 7 low-order products (<=2^-8 rel)
// chain in the persistent alo MFMA accumulator (bias ~2^-27|Y|, negligible).
// ============================================================================
__launch_bounds__(512, 4)
__global__ void lnn_mfma(
    const float* __restrict__ g_td, const float* __restrict__ g_sd,
    const float* __restrict__ g_th, const float* __restrict__ g_z,
    const float* __restrict__ g_s,  const float* __restrict__ g_sdd,
    const float* __restrict__ g_tau,
    const float* __restrict__ LW1, const float* __restrict__ Lb1,
    const float* __restrict__ Lb2, const float* __restrict__ LW3,
    const float* __restrict__ BW1, const float* __restrict__ Bb1,
    const float* __restrict__ BW2, const float* __restrict__ Bb2,
    const unsigned short* __restrict__ PL,
    float* __restrict__ out)
{
    __shared__ __align__(16) unsigned char ldsX[49152];   // 3 planes x 16KB (X1 then X2)
    __shared__ __align__(16) float h1L[16 * 260];         // h1[s][k], pad 260
    __shared__ __align__(16) float xs2[16][SB];
    __shared__ __align__(16) float redM[8][SB][18];       // [wave][s][H6 dL3 ct3 Hd6]
    __shared__ __align__(16) float red2[SB][3];

    const int tid = threadIdx.x;
    const int c   = tid & 63;
    const int r   = tid >> 6;        // wave 0..7
    const int l15 = c & 15;
    const int lq  = c >> 4;
    const int mt0 = r * 2;           // wave's first M-tile
    const int sg0 = blockIdx.x * SB;

    // ---------------- stage inputs ----------------
    if (tid < SB * 3) {
        int s = tid / 3, m = tid - s * 3;
        xs2[m][s]      = g_td [(sg0 + s) * 3 + m];
        xs2[3 + m][s]  = g_sd [(sg0 + s) * 3 + m];
        xs2[6 + m][s]  = g_th [(sg0 + s) * 3 + m];
        xs2[10 + m][s] = g_s  [(sg0 + s) * 3 + m];
        xs2[13 + m][s] = g_sdd[(sg0 + s) * 3 + m];
    } else if (tid < SB * 4) {
        int s = tid - SB * 3;
        xs2[9][s] = g_z[sg0 + s];
    }
    __syncthreads();

    // ---------------- phase A: h1 = tanh(x @ LW1 + b1) -> h1L ----------------
    {
        int kk = tid & 255;
        int sbase = (tid >> 8) * 8;
        float a1[8];
#pragma unroll
        for (int e = 0; e < 8; ++e) a1[e] = 0.0f;
#pragma unroll
        for (int m = 0; m < 10; ++m) {
            float w = LW1[m * HID + kk];
#pragma unroll
            for (int e = 0; e < 8; ++e)
                a1[e] = __builtin_fmaf(xs2[m][sbase + e], w, a1[e]);
        }
        float bb = Lb1[kk];
#pragma unroll
        for (int e = 0; e < 8; ++e)
            h1L[(sbase + e) * 260 + kk] = fast_tanh(a1[e] + bb);
    }

    // ---------------- B_NN (VALU, cheap): wave r -> samples {2r, 2r+1} ----------------
    {
        const int k0 = c * 4;
        const int s0 = r * 2;
        v2f ab[4];
#pragma unroll
        for (int q = 0; q < 4; ++q) ab[q] = (v2f){0.0f, 0.0f};
#pragma unroll
        for (int m = 0; m < 9; ++m) {
            v4f w4v = *(const v4f*)(BW1 + m * HID + k0);
            v2f wlo = __builtin_shufflevector(w4v, w4v, 0, 1);
            v2f whi = __builtin_shufflevector(w4v, w4v, 2, 3);
            int xi = (m < 3) ? (6 + m) : (7 + m);
            v2f xmv = *(const v2f*)&xs2[xi][s0];
            ACC4(ab, xmv);
        }
        v4f bbv = *(const v4f*)(Bb1 + k0);
        v2f bp0 = (v2f){0,0}, bp1 = (v2f){0,0}, bp2 = (v2f){0,0};
#pragma unroll
        for (int q = 0; q < 4; ++q) {
            int k = k0 + q;
            v2f hb2; hb2.x = fast_tanh(ab[q].x + bbv[q]); hb2.y = fast_tanh(ab[q].y + bbv[q]);
            bp0 += hb2 * BW2[k * 3 + 0];
            bp1 += hb2 * BW2[k * 3 + 1];
            bp2 += hb2 * BW2[k * 3 + 2];
        }
        bp0 = red64(bp0); bp1 = red64(bp1); bp2 = red64(bp2);
        if (c == 0) {
            red2[s0][0] = bp0.x; red2[s0 + 1][0] = bp0.y;
            red2[s0][1] = bp1.x; red2[s0 + 1][1] = bp1.y;
            red2[s0][2] = bp2.x; red2[s0 + 1][2] = bp2.y;
        }
    }
    __syncthreads();

    // ---------------- GEMM1: Y1[n][j] = sum_k LW2[k][n] * X1[j][k] ----------------
    // X1 columns j = f*16 + s: f=0 -> h1, f=1..3 -> t1*w1d_f. K halved for LDS.
    v4f acc[2][4], alo[2][4];
#pragma unroll
    for (int m = 0; m < 2; ++m)
#pragma unroll
        for (int b = 0; b < 4; ++b) { acc[m][b] = (v4f){0,0,0,0}; alo[m][b] = (v4f){0,0,0,0}; }

    for (int half = 0; half < 2; ++half) {
        // ---- build X1 planes for this K-half: thread (j=c, run=r) covers 16 k ----
        {
            int s = c & 15, f = c >> 4;
            int kb = half * 128 + r * 16;
            float vv[16];
#pragma unroll
            for (int qq = 0; qq < 4; ++qq) {
                v4f h4 = *(const v4f*)&h1L[s * 260 + kb + qq * 4];
                if (f == 0) {
#pragma unroll
                    for (int e = 0; e < 4; ++e) vv[qq * 4 + e] = h4[e];
                } else {
                    v4f wq = *(const v4f*)(LW1 + (f - 1) * HID + kb + qq * 4);
#pragma unroll
                    for (int e = 0; e < 4; ++e) vv[qq * 4 + e] = (1.0f - h4[e] * h4[e]) * wq[e];
                }
            }
            unsigned short sp[3][16];
#pragma unroll
            for (int e = 0; e < 16; ++e) split3(vv[e], sp[0][e], sp[1][e], sp[2][e]);
#pragma unroll
            for (int p = 0; p < 3; ++p)
#pragma unroll
                for (int bh = 0; bh < 2; ++bh) {
                    i32x4 pk;
#pragma unroll
                    for (int d = 0; d < 4; ++d)
                        pk[d] = (int)sp[p][bh * 8 + 2 * d] | ((int)sp[p][bh * 8 + 2 * d + 1] << 16);
                    *(i32x4*)(ldsX + x1_off(p, c, r * 2 + bh)) = pk;
                }
        }
        __syncthreads();
        // ---- 4 K-steps: 8-product Ozaki (hh via hazard-safe zero-C MFMA) ----
        for (int ksl = 0; ksl < 4; ++ksl) {
            int ksg = half * 4 + ksl;
            int kb16 = ksl * 4 + lq;
            const unsigned short* a0 = PL + mt0 * 4096 + ksg * 512 + c * 8;
            i32x4 Ah[2], Am[2], Al[2];
#pragma unroll
            for (int m = 0; m < 2; ++m) {
                Ah[m] = *(const i32x4*)(a0 + m * 4096);
                Am[m] = *(const i32x4*)(a0 + 65536 + m * 4096);
                Al[m] = *(const i32x4*)(a0 + 131072 + m * 4096);
            }
            // plane 0 (Bh): hh -> safe fold; mh, lh -> alo
#pragma unroll
            for (int b = 0; b < 4; ++b) {
                i32x4 B = *(const i32x4*)(ldsX + x1_off(0, b * 16 + l15, kb16));
                acc[0][b] += mfma_safe(Ah[0], B);
                acc[1][b] += mfma_safe(Ah[1], B);
                mfma_acc(alo[0][b], Am[0], B); mfma_acc(alo[1][b], Am[1], B);
                mfma_acc(alo[0][b], Al[0], B); mfma_acc(alo[1][b], Al[1], B);
            }
            // plane 1 (Bm): hm, mm, lm -> alo
#pragma unroll
            for (int b = 0; b < 4; ++b) {
                i32x4 B = *(const i32x4*)(ldsX + x1_off(1, b * 16 + l15, kb16));
                mfma_acc(alo[0][b], Ah[0], B); mfma_acc(alo[1][b], Ah[1], B);
                mfma_acc(alo[0][b], Am[0], B); mfma_acc(alo[1][b], Am[1], B);
                mfma_acc(alo[0][b], Al[0], B); mfma_acc(alo[1][b], Al[1], B);
            }
            // plane 2 (Bl): hl, ml -> alo
#pragma unroll
            for (int b = 0; b < 4; ++b) {
                i32x4 B = *(const i32x4*)(ldsX + x1_off(2, b * 16 + l15, kb16));
                mfma_acc(alo[0][b], Ah[0], B); mfma_acc(alo[1][b], Ah[1], B);
                mfma_acc(alo[0][b], Am[0], B); mfma_acc(alo[1][b], Am[1], B);
            }
        }
        __syncthreads();
    }
    mfma_read_fence();
#pragma unroll
    for (int m = 0; m < 2; ++m)
#pragma unroll
        for (int b = 0; b < 4; ++b) acc[m][b] += alo[m][b];

    // ---------------- epilogue 1: H quad part, X2 = {g2 rows 0-15, pd rows 16-31} ----------------
    // Lane holds all 4 families for (n = mt*16+lq*4+i, sample = l15): shuffle-free.
    float Hp[6] = {0, 0, 0, 0, 0, 0};
    const int sE = l15;
    const float td0s = xs2[0][sE], td1s = xs2[1][sE], td2s = xs2[2][sE];
#pragma unroll
    for (int m = 0; m < 2; ++m) {
        int nq = (mt0 + m) * 16 + lq * 4;
        v4f b2 = *(const v4f*)(Lb2 + nq);
        v4f w3 = *(const v4f*)(LW3 + nq);
        unsigned short sg[3][4], sd[3][4];
#pragma unroll
        for (int i = 0; i < 4; ++i) {
            float a2 = acc[m][0][i] + b2[i];
            float P0 = acc[m][1][i], P1 = acc[m][2][i], P2 = acc[m][3][i];
            float h2 = fast_tanh(a2);
            float t2 = 1.0f - h2 * h2;
            float g2 = t2 * w3[i];
            float m2 = -2.0f * h2 * g2;
            Hp[0] += m2 * P0 * P0; Hp[1] += m2 * P0 * P1; Hp[2] += m2 * P1 * P1;
            Hp[3] += m2 * P0 * P2; Hp[4] += m2 * P1 * P2; Hp[5] += m2 * P2 * P2;
            float pd = m2 * (P0 * td0s + P1 * td1s + P2 * td2s);
            split3(g2, sg[0][i], sg[1][i], sg[2][i]);
            split3(pd, sd[0][i], sd[1][i], sd[2][i]);
        }
        int kb16 = (mt0 + m) * 2 + (lq >> 1);
        int off8 = (lq & 1) * 8;
#pragma unroll
        for (int p = 0; p < 3; ++p) {
            i32x2 a, bpk;
            a[0]   = (int)sg[p][0] | ((int)sg[p][1] << 16);
            a[1]   = (int)sg[p][2] | ((int)sg[p][3] << 16);
            bpk[0] = (int)sd[p][0] | ((int)sd[p][1] << 16);
            bpk[1] = (int)sd[p][2] | ((int)sd[p][3] << 16);
            *(i32x2*)(ldsX + x2_off(p, sE, kb16) + off8)      = a;
            *(i32x2*)(ldsX + x2_off(p, 16 + sE, kb16) + off8) = bpk;
        }
    }
#pragma unroll
    for (int j = 0; j < 6; ++j) {
        float v = red_lq(Hp[j]);
        if (lq == 0) redM[r][sE][j] = v;
    }
    __syncthreads();

    // ---------------- GEMM2: Y2[k][j2] = sum_n LW2[k][n] * X2[j2][n] ----------------
    v4f acc2[2][2], alo2[2][2];
#pragma unroll
    for (int m = 0; m < 2; ++m)
#pragma unroll
        for (int b = 0; b < 2; ++b) { acc2[m][b] = (v4f){0,0,0,0}; alo2[m][b] = (v4f){0,0,0,0}; }

    for (int ks = 0; ks < 8; ++ks) {
        int kb16 = ks * 4 + lq;
        const unsigned short* a0 = PL + 196608 + mt0 * 4096 + ks * 512 + c * 8;
        i32x4 Ah[2], Am[2], Al[2];
#pragma unroll
        for (int m = 0; m < 2; ++m) {
            Ah[m] = *(const i32x4*)(a0 + m * 4096);
            Am[m] = *(const i32x4*)(a0 + 65536 + m * 4096);
            Al[m] = *(const i32x4*)(a0 + 131072 + m * 4096);
        }
        // plane 0 (Bh): hh -> safe fold; mh, lh -> alo
#pragma unroll
        for (int b = 0; b < 2; ++b) {
            i32x4 B = *(const i32x4*)(ldsX + x2_off(0, b * 16 + l15, kb16));
            acc2[0][b] += mfma_safe(Ah[0], B);
            acc2[1][b] += mfma_safe(Ah[1], B);
            mfma_acc(alo2[0][b], Am[0], B); mfma_acc(alo2[1][b], Am[1], B);
            mfma_acc(alo2[0][b], Al[0], B); mfma_acc(alo2[1][b], Al[1], B);
        }
        // plane 1 (Bm)
#pragma unroll
        for (int b = 0; b < 2; ++b) {
            i32x4 B = *(const i32x4*)(ldsX + x2_off(1, b * 16 + l15, kb16));
            mfma_acc(alo2[0][b], Ah[0], B); mfma_acc(alo2[1][b], Ah[1], B);
            mfma_acc(alo2[0][b], Am[0], B); mfma_acc(alo2[1][b], Am[1], B);
            mfma_acc(alo2[0][b], Al[0], B); mfma_acc(alo2[1][b], Al[1], B);
        }
        // plane 2 (Bl)
#pragma unroll
        for (int b = 0; b < 2; ++b) {
            i32x4 B = *(const i32x4*)(ldsX + x2_off(2, b * 16 + l15, kb16));
            mfma_acc(alo2[0][b], Ah[0], B); mfma_acc(alo2[1][b], Ah[1], B);
            mfma_acc(alo2[0][b], Am[0], B); mfma_acc(alo2[1][b], Am[1], B);
        }
    }
    mfma_read_fence();
#pragma unroll
    for (int m = 0; m < 2; ++m)
#pragma unroll
        for (int b = 0; b < 2; ++b) acc2[m][b] += alo2[m][b];

    // ---------------- epilogue 2: dL, C*td, H diag part (shuffle-free) ----------------
    {
        v4f dl0 = (v4f){0,0,0,0}, dl1 = dl0, dl2 = dl0;
        v4f ct0 = dl0, ct1 = dl0, ct2 = dl0;
        v4f hd[6];
#pragma unroll
        for (int j = 0; j < 6; ++j) hd[j] = (v4f){0,0,0,0};
#pragma unroll
        for (int m = 0; m < 2; ++m) {
            int kq = (mt0 + m) * 16 + lq * 4;
            v4f U = acc2[m][0];
            v4f W = acc2[m][1];
            v4f h1 = *(const v4f*)&h1L[sE * 260 + kq];
            v4f wd0 = *(const v4f*)(LW1 + 0 * HID + kq);
            v4f wd1 = *(const v4f*)(LW1 + 1 * HID + kq);
            v4f wd2 = *(const v4f*)(LW1 + 2 * HID + kq);
            v4f wt0 = *(const v4f*)(LW1 + 6 * HID + kq);
            v4f wt1 = *(const v4f*)(LW1 + 7 * HID + kq);
            v4f wt2 = *(const v4f*)(LW1 + 8 * HID + kq);
            v4f t1 = 1.0f - h1 * h1;
            v4f g1 = U * t1;
            dl0 += g1 * wt0; dl1 += g1 * wt1; dl2 += g1 * wt2;
            v4f cf = -2.0f * U * h1 * t1;
            v4f wdtd = td0s * wd0 + td1s * wd1 + td2s * wd2;
            v4f ct = t1 * W + cf * wdtd;
            ct0 += ct * wt0; ct1 += ct * wt1; ct2 += ct * wt2;
            hd[0] += cf * wd0 * wd0; hd[1] += cf * wd0 * wd1; hd[2] += cf * wd1 * wd1;
            hd[3] += cf * wd0 * wd2; hd[4] += cf * wd1 * wd2; hd[5] += cf * wd2 * wd2;
        }
        float vals[12];
        vals[0] = hsum4(dl0); vals[1] = hsum4(dl1); vals[2] = hsum4(dl2);
        vals[3] = hsum4(ct0); vals[4] = hsum4(ct1); vals[5] = hsum4(ct2);
#pragma unroll
        for (int j = 0; j < 6; ++j) vals[6 + j] = hsum4(hd[j]);
#pragma unroll
        for (int j = 0; j < 12; ++j) {
            float v = red_lq(vals[j]);
            if (lq == 0) redM[r][sE][6 + j] = v;
        }
    }
    __syncthreads();

    // ---------------- per-sample 3x3 symmetric solve (fp64) ----------------
    if (tid < SB) {
        int s = tid;
        int gs = sg0 + s;
        double Ha = 0, Hb = 0, Hd = 0, Hc = 0, He = 0, Hf = 0;
        double dL0 = 0, dL1 = 0, dL2 = 0, ct0 = 0, ct1 = 0, ct2 = 0;
#pragma unroll
        for (int w = 0; w < 8; ++w) {
            Ha += (double)redM[w][s][0] + (double)redM[w][s][12];
            Hb += (double)redM[w][s][1] + (double)redM[w][s][13];
            Hd += (double)redM[w][s][2] + (double)redM[w][s][14];
            Hc += (double)redM[w][s][3] + (double)redM[w][s][15];
            He += (double)redM[w][s][4] + (double)redM[w][s][16];
            Hf += (double)redM[w][s][5] + (double)redM[w][s][17];
            dL0 += redM[w][s][6]; dL1 += redM[w][s][7]; dL2 += redM[w][s][8];
            ct0 += redM[w][s][9]; ct1 += redM[w][s][10]; ct2 += redM[w][s][11];
        }
        double rhs[3];
        rhs[0] = (double)g_tau[gs * 3 + 0] + (double)red2[s][0] + (double)Bb2[0] + dL0 - ct0;
        rhs[1] = (double)g_tau[gs * 3 + 1] + (double)red2[s][1] + (double)Bb2[1] + dL1 - ct1;
        rhs[2] = (double)g_tau[gs * 3 + 2] + (double)red2[s][2] + (double)Bb2[2] + dL2 - ct2;
        double I00 = Hd * Hf - He * He;
        double I01 = Hc * He - Hb * Hf;
        double I02 = Hb * He - Hc * Hd;
        double I11 = Ha * Hf - Hc * Hc;
        double I12 = Hb * Hc - Ha * He;
        double I22 = Ha * Hd - Hb * Hb;
        double det = Ha * I00 + Hb * I01 + Hc * I02;
        double inv = 1.0 / det;
        out[gs * 3 + 0] = (float)((I00 * rhs[0] + I01 * rhs[1] + I02 * rhs[2]) * inv);
        out[gs * 3 + 1] = (float)((I01 * rhs[0] + I11 * rhs[1] + I12 * rhs[2]) * inv);
        out[gs * 3 + 2] = (float)((I02 * rhs[0] + I12 * rhs[1] + I22 * rhs[2]) * inv);
    }
}

// ============================================================================
// fallback path (Round-3 VALU kernel, used only if ws_size too small)
// ============================================================================
__global__ void transpose256(const float* __restrict__ in, float* __restrict__ outT) {
    __shared__ float tile[32][33];
    const int tid = threadIdx.x;
    const int bx = blockIdx.x & 7;
    const int by = blockIdx.x >> 3;
    const int tx = tid & 31, ty = tid >> 5;
#pragma unroll
    for (int yy = ty; yy < 32; yy += 8)
        tile[yy][tx] = in[(by * 32 + yy) * HID + bx * 32 + tx];
    __syncthreads();
#pragma unroll
    for (int yy = ty; yy < 32; yy += 8)
        outT[(bx * 32 + yy) * HID + by * 32 + tx] = tile[tx][yy];
}

__device__ __forceinline__ v2f pk_mul_lo(v2f a, v2f b) {
    v2f d;
    asm("v_pk_mul_f32 %0, %1, %2 op_sel_hi:[1,0]" : "=v"(d) : "v"(a), "v"(b));
    return d;
}
__device__ __forceinline__ v2f pk_mul_hi(v2f a, v2f b) {
    v2f d;
    asm("v_pk_mul_f32 %0, %1, %2 op_sel:[0,1] op_sel_hi:[1,1]" : "=v"(d) : "v"(a), "v"(b));
    return d;
}

__launch_bounds__(256, 4)
__global__ void lnn_valu(
    const float* __restrict__ g_td, const float* __restrict__ g_sd,
    const float* __restrict__ g_th, const float* __restrict__ g_z,
    const float* __restrict__ g_s,  const float* __restrict__ g_sdd,
    const float* __restrict__ g_tau,
    const float* __restrict__ LW1, const float* __restrict__ Lb1,
    const float* __restrict__ LW2, const float* __restrict__ Lb2,
    const float* __restrict__ LW3,
    const float* __restrict__ BW1, const float* __restrict__ Bb1,
    const float* __restrict__ BW2, const float* __restrict__ Bb2,
    const float* __restrict__ W2T,
    float* __restrict__ out)
{
    __shared__ __align__(16) float ldsP[HID * 32];
    __shared__ __align__(16) float xs2[16][8];
    __shared__ __align__(16) float red[8][16];

    const int tid = threadIdx.x;
    const int c   = tid & 63;
    const int r   = tid >> 6;
    const int k0  = c * 4;
    const int s0  = r * 2;
    const int sg0 = blockIdx.x * 8;
    const int o1  = r * 8;
    const int o2  = r * 4;
    const int sw1 = (c & 3) << 3;
    const int sw2 = (c & 3) << 2;

    if (tid < 24) {
        int s = tid / 3, m = tid - s * 3;
        xs2[m][s]      = g_td [(sg0 + s) * 3 + m];
        xs2[3 + m][s]  = g_sd [(sg0 + s) * 3 + m];
        xs2[6 + m][s]  = g_th [(sg0 + s) * 3 + m];
        xs2[10 + m][s] = g_s  [(sg0 + s) * 3 + m];
        xs2[13 + m][s] = g_sdd[(sg0 + s) * 3 + m];
    } else if (tid < 32) {
        int s = tid - 24;
        xs2[9][s] = g_z[sg0 + s];
    }
    __syncthreads();

    float h1r[2][4];
    {
        v2f a1[4];
#pragma unroll
        for (int q = 0; q < 4; ++q) a1[q] = (v2f){0.0f, 0.0f};
#pragma unroll
        for (int m = 0; m < 10; ++m) {
            v4f w4 = *(const v4f*)(LW1 + m * HID + k0);
            v2f wlo = __builtin_shufflevector(w4, w4, 0, 1);
            v2f whi = __builtin_shufflevector(w4, w4, 2, 3);
            v2f xmv = *(const v2f*)&xs2[m][s0];
            ACC4(a1, xmv);
        }
        v4f bb  = *(const v4f*)(Lb1 + k0);
        v4f wd0 = *(const v4f*)(LW1 + 0 * HID + k0);
        v4f wd1 = *(const v4f*)(LW1 + 1 * HID + k0);
        v4f wd2 = *(const v4f*)(LW1 + 2 * HID + k0);
#pragma unroll
        for (int q = 0; q < 4; ++q) {
            float hx = fast_tanh(a1[q].x + bb[q]);
            float hy = fast_tanh(a1[q].y + bb[q]);
            h1r[0][q] = hx; h1r[1][q] = hy;
            float tx = 1.0f - hx * hx, ty = 1.0f - hy * hy;
            int rb = (k0 + q) * 32 + (o1 ^ sw1);
            *(v4f*)&ldsP[rb]     = (v4f){ hx, hy, tx * wd0[q], ty * wd0[q] };
            *(v4f*)&ldsP[rb + 4] = (v4f){ tx * wd1[q], ty * wd1[q], tx * wd2[q], ty * wd2[q] };
        }
    }

    {
        v2f ab[4];
#pragma unroll
        for (int q = 0; q < 4; ++q) ab[q] = (v2f){0.0f, 0.0f};
#pragma unroll
        for (int m = 0; m < 9; ++m) {
            v4f w4 = *(const v4f*)(BW1 + m * HID + k0);
            v2f wlo = __builtin_shufflevector(w4, w4, 0, 1);
            v2f whi = __builtin_shufflevector(w4, w4, 2, 3);
            int xi = (m < 3) ? (6 + m) : (7 + m);
            v2f xmv = *(const v2f*)&xs2[xi][s0];
            ACC4(ab, xmv);
        }
        v4f bbv = *(const v4f*)(Bb1 + k0);
        v2f bp0 = (v2f){0,0}, bp1 = (v2f){0,0}, bp2 = (v2f){0,0};
#pragma unroll
        for (int q = 0; q < 4; ++q) {
            int k = k0 + q;
            v2f hb; hb.x = fast_tanh(ab[q].x + bbv[q]); hb.y = fast_tanh(ab[q].y + bbv[q]);
            bp0 += hb * BW2[k * 3 + 0];
            bp1 += hb * BW2[k * 3 + 1];
            bp2 += hb * BW2[k * 3 + 2];
        }
        bp0 = red64(bp0); bp1 = red64(bp1); bp2 = red64(bp2);
        if (c == 0) {
            red[s0][12] = bp0.x; red[s0 + 1][12] = bp0.y;
            red[s0][13] = bp1.x; red[s0 + 1][13] = bp1.y;
            red[s0][14] = bp2.x; red[s0 + 1][14] = bp2.y;
        }
    }
    __syncthreads();

    v2f acc[4][4];
#pragma unroll
    for (int f = 0; f < 4; ++f)
#pragma unroll
        for (int q = 0; q < 4; ++q) acc[f][q] = (v2f){0.0f, 0.0f};

    for (int n0 = 0; n0 < HID; n0 += 4) {
        const float* prow = &ldsP[n0 * 32 + (o1 ^ (((n0 >> 2) & 3) << 3))];
        const float* wrow = LW2 + n0 * HID + k0;
#pragma unroll
        for (int j = 0; j < 4; ++j) {
            v4f pA = *(const v4f*)(prow + j * 32);
            v4f pB = *(const v4f*)(prow + j * 32 + 4);
            v4f w4 = *(const v4f*)(wrow + j * HID);
            v2f wlo = __builtin_shufflevector(w4, w4, 0, 1);
            v2f whi = __builtin_shufflevector(w4, w4, 2, 3);
            v2f hv = __builtin_shufflevector(pA, pA, 0, 1);
            v2f i1 = __builtin_shufflevector(pA, pA, 2, 3);
            v2f i2 = __builtin_shufflevector(pB, pB, 0, 1);
            v2f i3 = __builtin_shufflevector(pB, pB, 2, 3);
            ACC4(acc[0], hv);
            ACC4(acc[1], i1);
            ACC4(acc[2], i2);
            ACC4(acc[3], i3);
        }
    }
    __syncthreads();

    v2f Hp[6];
#pragma unroll
    for (int i = 0; i < 6; ++i) Hp[i] = (v2f){0.0f, 0.0f};
    const v2f td0v = *(const v2f*)&xs2[0][s0];
    const v2f td1v = *(const v2f*)&xs2[1][s0];
    const v2f td2v = *(const v2f*)&xs2[2][s0];
    {
        v4f b2v = *(const v4f*)(Lb2 + k0);
        v4f w3v = *(const v4f*)(LW3 + k0);
#pragma unroll
        for (int q = 0; q < 4; ++q) {
            v2f a2 = acc[0][q] + b2v[q];
            v2f h2; h2.x = fast_tanh(a2.x); h2.y = fast_tanh(a2.y);
            v2f t2 = 1.0f - h2 * h2;
            v2f g2 = t2 * w3v[q];
            v2f m2 = -2.0f * h2 * g2;
            v2f P0 = acc[1][q], P1 = acc[2][q], P2 = acc[3][q];
            v2f m2P0 = m2 * P0, m2P1 = m2 * P1;
            Hp[0] += m2P0 * P0;
            Hp[1] += m2P0 * P1;
            Hp[2] += m2P1 * P1;
            Hp[3] += m2P0 * P2;
            Hp[4] += m2P1 * P2;
            Hp[5] += m2 * P2 * P2;
            v2f ptd = td0v * P0 + td1v * P1 + td2v * P2;
            v2f pd  = m2 * ptd;
            *(v4f*)&ldsP[(k0 + q) * 32 + (o2 ^ sw2)] = (v4f){ g2.x, g2.y, pd.x, pd.y };
        }
    }
    __syncthreads();

#pragma unroll
    for (int f = 0; f < 2; ++f)
#pragma unroll
        for (int q = 0; q < 4; ++q) acc[f][q] = (v2f){0.0f, 0.0f};

    for (int n0 = 0; n0 < HID; n0 += 4) {
        const float* prow = &ldsP[n0 * 32 + (o2 ^ (((n0 >> 2) & 3) << 2))];
        const float* wrow = W2T + n0 * HID + k0;
#pragma unroll
        for (int j = 0; j < 4; ++j) {
            v4f p  = *(const v4f*)(prow + j * 32);
            v4f w4 = *(const v4f*)(wrow + j * HID);
            v2f wlo = __builtin_shufflevector(w4, w4, 0, 1);
            v2f whi = __builtin_shufflevector(w4, w4, 2, 3);
            v2f g2v = __builtin_shufflevector(p, p, 0, 1);
            v2f pdv = __builtin_shufflevector(p, p, 2, 3);
            ACC4(acc[0], g2v);
            ACC4(acc[1], pdv);
        }
    }

    v2f dLp[3], ctp[3];
#pragma unroll
    for (int i = 0; i < 3; ++i) { dLp[i] = (v2f){0,0}; ctp[i] = (v2f){0,0}; }
    {
        v4f wd0 = *(const v4f*)(LW1 + 0 * HID + k0);
        v4f wd1 = *(const v4f*)(LW1 + 1 * HID + k0);
        v4f wd2 = *(const v4f*)(LW1 + 2 * HID + k0);
        v4f wt0 = *(const v4f*)(LW1 + 6 * HID + k0);
        v4f wt1 = *(const v4f*)(LW1 + 7 * HID + k0);
        v4f wt2 = *(const v4f*)(LW1 + 8 * HID + k0);
#pragma unroll
        for (int q = 0; q < 4; ++q) {
            v2f h1; h1.x = h1r[0][q]; h1.y = h1r[1][q];
            v2f t1 = 1.0f - h1 * h1;
            v2f u  = acc[0][q];
            v2f w  = acc[1][q];
            v2f g1 = u * t1;
            dLp[0] += g1 * wt0[q]; dLp[1] += g1 * wt1[q]; dLp[2] += g1 * wt2[q];
            v2f cf = -2.0f * u * h1 * t1;
            v2f wdtd = td0v * wd0[q] + td1v * wd1[q] + td2v * wd2[q];
            v2f ct = t1 * w + cf * wdtd;
            ctp[0] += ct * wt0[q]; ctp[1] += ct * wt1[q]; ctp[2] += ct * wt2[q];
            float w00 = wd0[q] * wd0[q], w01 = wd0[q] * wd1[q], w11 = wd1[q] * wd1[q];
            float w02 = wd0[q] * wd2[q], w12 = wd1[q] * wd2[q], w22 = wd2[q] * wd2[q];
            Hp[0] += cf * w00; Hp[1] += cf * w01; Hp[2] += cf * w11;
            Hp[3] += cf * w02; Hp[4] += cf * w12; Hp[5] += cf * w22;
        }
    }

#pragma unroll
    for (int i = 0; i < 6; ++i) {
        v2f v = red64(Hp[i]);
        if (c == 0) { red[s0][i] = v.x; red[s0 + 1][i] = v.y; }
    }
#pragma unroll
    for (int i = 0; i < 3; ++i) {
        v2f v = red64(dLp[i]);
        if (c == 0) { red[s0][6 + i] = v.x; red[s0 + 1][6 + i] = v.y; }
    }
#pragma unroll
    for (int i = 0; i < 3; ++i) {
        v2f v = red64(ctp[i]);
        if (c == 0) { red[s0][9 + i] = v.x; red[s0 + 1][9 + i] = v.y; }
    }
    __syncthreads();

    if (tid < 8) {
        int s = tid;
        int gs = sg0 + s;
        double Ha = red[s][0], Hb = red[s][1], Hd = red[s][2];
        double Hc = red[s][3], He = red[s][4], Hf = red[s][5];
        double rhs[3];
#pragma unroll
        for (int i = 0; i < 3; ++i) {
            rhs[i] = (double)g_tau[gs * 3 + i] + (double)red[s][12 + i] + (double)Bb2[i]
                   + (double)red[s][6 + i]
                   - (double)red[s][9 + i];
        }
        double I00 = Hd * Hf - He * He;
        double I01 = Hc * He - Hb * Hf;
        double I02 = Hb * He - Hc * Hd;
        double I11 = Ha * Hf - Hc * Hc;
        double I12 = Hb * Hc - Ha * He;
        double I22 = Ha * Hd - Hb * Hb;
        double det = Ha * I00 + Hb * I01 + Hc * I02;
        double inv = 1.0 / det;
        out[gs * 3 + 0] = (float)((I00 * rhs[0] + I01 * rhs[1] + I02 * rhs[2]) * inv);
        out[gs * 3 + 1] = (float)((I01 * rhs[0] + I11 * rhs[1] + I12 * rhs[2]) * inv);
        out[gs * 3 + 2] = (float)((I02 * rhs[0] + I12 * rhs[1] + I22 * rhs[2]) * inv);
    }
}

extern "C" void kernel_launch(void* const* d_in, const int* in_sizes, int n_in,
                              void* d_out, int out_size, void* d_ws, size_t ws_size,
                              hipStream_t stream) {
    const float* td  = (const float*)d_in[0];
    const float* sd  = (const float*)d_in[1];
    const float* th  = (const float*)d_in[2];
    const float* z   = (const float*)d_in[3];
    const float* s_  = (const float*)d_in[4];
    const float* sdd = (const float*)d_in[5];
    const float* tau = (const float*)d_in[6];
    const float* LW1 = (const float*)d_in[7];
    const float* Lb1 = (const float*)d_in[8];
    const float* LW2 = (const float*)d_in[9];
    const float* Lb2 = (const float*)d_in[10];
    const float* LW3 = (const float*)d_in[11];
    // d_in[12] = Lb3 (constant bias: no effect on derivatives)
    const float* BW1 = (const float*)d_in[13];
    const float* Bb1 = (const float*)d_in[14];
    const float* BW2 = (const float*)d_in[15];
    const float* Bb2 = (const float*)d_in[16];
    float* outp = (float*)d_out;

    const int Btot = in_sizes[0] / 3;

    if (ws_size >= 6u * 65536u * 2u) {
        unsigned short* planes = (unsigned short*)d_ws;   // 6 x 128KB bf16 planes
        build_planes<<<dim3(64), dim3(256), 0, stream>>>(LW2, planes);
        const int nblk = Btot / SB;
        lnn_mfma<<<dim3(nblk), dim3(512), 0, stream>>>(
            td, sd, th, z, s_, sdd, tau, LW1, Lb1, Lb2, LW3,
            BW1, Bb1, BW2, Bb2, planes, outp);
    } else {
        float* W2T = (float*)d_ws;
        transpose256<<<dim3(64), dim3(256), 0, stream>>>(LW2, W2T);
        const int nblk = Btot / 8;
        lnn_valu<<<dim3(nblk), dim3(256), 0, stream>>>(
            td, sd, th, z, s_, sdd, tau, LW1, Lb1, LW2, Lb2, LW3,
            BW1, Bb1, BW2, Bb2, W2T, outp);
    }
}

// Round 10
// 627.207 us; speedup vs baseline: 1.1513x; 1.1513x over previous
//
#include <hip/hip_runtime.h>

#define HID 256
#define SB  16      // samples per block (512 threads, 8 waves)

typedef float v2f __attribute__((ext_vector_type(2)));
typedef float v4f __attribute__((ext_vector_type(4)));
typedef int   i32x4 __attribute__((ext_vector_type(4)));
typedef int   i32x2 __attribute__((ext_vector_type(2)));

__device__ __forceinline__ float fast_tanh(float x) {
    float ax = __builtin_fabsf(x);
    float e  = __expf(2.0f * ax);
    float t  = 1.0f - 2.0f * __builtin_amdgcn_rcpf(e + 1.0f);
    return __builtin_copysignf(t, x);
}

__device__ __forceinline__ v2f pk_fma_lo(v2f a, v2f b, v2f c) {
    asm("v_pk_fma_f32 %0, %1, %2, %0 op_sel_hi:[1,0,1]" : "+v"(c) : "v"(a), "v"(b));
    return c;
}
__device__ __forceinline__ v2f pk_fma_hi(v2f a, v2f b, v2f c) {
    asm("v_pk_fma_f32 %0, %1, %2, %0 op_sel:[0,1,0] op_sel_hi:[1,1,1]" : "+v"(c) : "v"(a), "v"(b));
    return c;
}

__device__ __forceinline__ v2f red64(v2f v) {
#pragma unroll
    for (int m = 1; m < 64; m <<= 1) {
        v.x += __shfl_xor(v.x, m, 64);
        v.y += __shfl_xor(v.y, m, 64);
    }
    return v;
}

__device__ __forceinline__ float red_lq(float v) {
    v += __shfl_xor(v, 16, 64);
    v += __shfl_xor(v, 32, 64);
    return v;
}

__device__ __forceinline__ float hsum4(v4f v) { return (v.x + v.y) + (v.z + v.w); }

// exact 3-way bf16 split (RNE): x ~= h + m + l, residual <= 2^-25 |x|
__device__ __forceinline__ void split3(float x, unsigned short& h, unsigned short& m, unsigned short& l) {
    unsigned u0 = __float_as_uint(x);
    unsigned short hh = (unsigned short)((u0 + 0x7FFFu + ((u0 >> 16) & 1u)) >> 16);
    float r1 = x - __uint_as_float((unsigned)hh << 16);
    unsigned u1 = __float_as_uint(r1);
    unsigned short mm = (unsigned short)((u1 + 0x7FFFu + ((u1 >> 16) & 1u)) >> 16);
    float r2 = r1 - __uint_as_float((unsigned)mm << 16);
    unsigned u2 = __float_as_uint(r2);
    unsigned short ll = (unsigned short)((u2 + 0x7FFFu + ((u2 >> 16) & 1u)) >> 16);
    h = hh; m = mm; l = ll;
}

// Chained-accumulate MFMA (D += A*B in the MFMA C path). MFMA->MFMA same-dest
// chaining needs no waits; first use after VALU zero-init is separated by loads.
__device__ __forceinline__ void mfma_acc(v4f& d, i32x4 a, i32x4 b) {
    asm("v_mfma_f32_16x16x32_bf16 %0, %1, %2, %0" : "+v"(d) : "v"(a), "v"(b));
}

// Hazard-safe zero-C MFMA whose result is immediately VALU-readable: the s_nops
// live INSIDE the asm blob so no compiler scheduling can shrink the distance.
// s_nop 1 covers VALU(zero-init)->MFMA SrcC read; s_nop 7+3 (12 states) covers
// MFMA->VALU read of D (4-pass XDL needs ~6).
__device__ __forceinline__ v4f mfma_safe(i32x4 a, i32x4 b) {
    v4f d = (v4f){0.0f, 0.0f, 0.0f, 0.0f};
    asm("s_nop 1\n\tv_mfma_f32_16x16x32_bf16 %0, %1, %2, %0\n\ts_nop 7\n\ts_nop 3"
        : "+v"(d) : "v"(a), "v"(b));
    return d;
}

// Standalone wait barrier before VALU-reading long-chained MFMA accumulators.
__device__ __forceinline__ void mfma_read_fence() {
    asm volatile("s_nop 7\n\ts_nop 3" ::: "memory");
}

// LDS byte offsets with FULL-granule XOR swizzle (R9 bank-conflict fix).
// Bijective in kb16 per row -> same function for writes and reads.
// X1: 64 rows x 256B (16 granules); X2: 32 rows x 512B (32 granules). Plane = 16KB.
__device__ __forceinline__ int x1_off(int p, int j, int kb16) {
    int g = (kb16 ^ (j & 15) ^ ((j >> 4) << 2)) & 15;
    return p * 16384 + j * 256 + (g << 4);
}
__device__ __forceinline__ int x2_off(int p, int j2, int kb16) {
    int g = (kb16 ^ (j2 & 15) ^ ((j2 >> 4) << 3)) & 31;
    return p * 16384 + j2 * 512 + (g << 4);
}

#define ACC4(DST, SRC) \
    DST[0] = pk_fma_lo(SRC, wlo, DST[0]); \
    DST[1] = pk_fma_hi(SRC, wlo, DST[1]); \
    DST[2] = pk_fma_lo(SRC, whi, DST[2]); \
    DST[3] = pk_fma_hi(SRC, whi, DST[3]);

// ============================================================================
// pre-kernel: split LW2 into 6 fragment-ordered bf16 planes (d_ws).
// tensor 0 (GEMM1 A): A1[n][k] = LW2[k][n]; tensor 1 (GEMM2 A): A2[k][n] row-major.
// frag: pos = (Mt*8 + ks)*64 + lane, elem = A[Mt*16+(lane&15)][ks*32+(lane>>4)*8+i]
// ============================================================================
__global__ void build_planes(const float* __restrict__ LW2, unsigned short* __restrict__ P) {
    int t = blockIdx.x * 256 + threadIdx.x;   // 0..16383
    int tensor = t >> 13;
    int pos = t & 8191;
    int l = pos & 63, ks = (pos >> 6) & 7, Mt = pos >> 9;
    int mrow = Mt * 16 + (l & 15);
    int kb = ks * 32 + ((l >> 4) << 3);
    unsigned short sh[3][8];
#pragma unroll
    for (int i = 0; i < 8; ++i) {
        float v = tensor ? LW2[mrow * HID + kb + i] : LW2[(kb + i) * HID + mrow];
        split3(v, sh[0][i], sh[1][i], sh[2][i]);
    }
#pragma unroll
    for (int p = 0; p < 3; ++p) {
        unsigned short* dst = P + (tensor * 3 + p) * 65536 + pos * 8;
#pragma unroll
        for (int i = 0; i < 8; ++i) dst[i] = sh[p][i];
    }
}

// ============================================================================
// main MFMA kernel: 512 threads, 8 waves, SB=16, wave owns 2 M-tiles.
// Precision (R10): 6-product Ozaki {hh, hm, mh, hl, lh, mm} — ml/lm dropped
// (~2^-24|Y|, same class as split residual; R4 vs R5 bit-identical absmax
// bounds their contribution below one bf16 output quantum). hh goes through
// mfma_safe (chain 1) + VALU RNE fold; the 5 low-order products chain in the
// persistent alo MFMA accumulator.
// ============================================================================
__launch_bounds__(512, 4)
__global__ void lnn_mfma(
    const float* __restrict__ g_td, const float* __restrict__ g_sd,
    const float* __restrict__ g_th, const float* __restrict__ g_z,
    const float* __restrict__ g_s,  const float* __restrict__ g_sdd,
    const float* __restrict__ g_tau,
    const float* __restrict__ LW1, const float* __restrict__ Lb1,
    const float* __restrict__ Lb2, const float* __restrict__ LW3,
    const float* __restrict__ BW1, const float* __restrict__ Bb1,
    const float* __restrict__ BW2, const float* __restrict__ Bb2,
    const unsigned short* __restrict__ PL,
    float* __restrict__ out)
{
    __shared__ __align__(16) unsigned char ldsX[49152];   // 3 planes x 16KB (X1 then X2)
    __shared__ __align__(16) float h1L[16 * 260];         // h1[s][k], pad 260
    __shared__ __align__(16) float xs2[16][SB];
    __shared__ __align__(16) float redM[8][SB][18];       // [wave][s][H6 dL3 ct3 Hd6]
    __shared__ __align__(16) float red2[SB][3];

    const int tid = threadIdx.x;
    const int c   = tid & 63;
    const int r   = tid >> 6;        // wave 0..7
    const int l15 = c & 15;
    const int lq  = c >> 4;
    const int mt0 = r * 2;           // wave's first M-tile
    const int sg0 = blockIdx.x * SB;

    // ---------------- stage inputs ----------------
    if (tid < SB * 3) {
        int s = tid / 3, m = tid - s * 3;
        xs2[m][s]      = g_td [(sg0 + s) * 3 + m];
        xs2[3 + m][s]  = g_sd [(sg0 + s) * 3 + m];
        xs2[6 + m][s]  = g_th [(sg0 + s) * 3 + m];
        xs2[10 + m][s] = g_s  [(sg0 + s) * 3 + m];
        xs2[13 + m][s] = g_sdd[(sg0 + s) * 3 + m];
    } else if (tid < SB * 4) {
        int s = tid - SB * 3;
        xs2[9][s] = g_z[sg0 + s];
    }
    __syncthreads();

    // ---------------- phase A: h1 = tanh(x @ LW1 + b1) -> h1L ----------------
    {
        int kk = tid & 255;
        int sbase = (tid >> 8) * 8;
        float a1[8];
#pragma unroll
        for (int e = 0; e < 8; ++e) a1[e] = 0.0f;
#pragma unroll
        for (int m = 0; m < 10; ++m) {
            float w = LW1[m * HID + kk];
#pragma unroll
            for (int e = 0; e < 8; ++e)
                a1[e] = __builtin_fmaf(xs2[m][sbase + e], w, a1[e]);
        }
        float bb = Lb1[kk];
#pragma unroll
        for (int e = 0; e < 8; ++e)
            h1L[(sbase + e) * 260 + kk] = fast_tanh(a1[e] + bb);
    }

    // ---------------- B_NN (VALU, cheap): wave r -> samples {2r, 2r+1} ----------------
    {
        const int k0 = c * 4;
        const int s0 = r * 2;
        v2f ab[4];
#pragma unroll
        for (int q = 0; q < 4; ++q) ab[q] = (v2f){0.0f, 0.0f};
#pragma unroll
        for (int m = 0; m < 9; ++m) {
            v4f w4v = *(const v4f*)(BW1 + m * HID + k0);
            v2f wlo = __builtin_shufflevector(w4v, w4v, 0, 1);
            v2f whi = __builtin_shufflevector(w4v, w4v, 2, 3);
            int xi = (m < 3) ? (6 + m) : (7 + m);
            v2f xmv = *(const v2f*)&xs2[xi][s0];
            ACC4(ab, xmv);
        }
        v4f bbv = *(const v4f*)(Bb1 + k0);
        v2f bp0 = (v2f){0,0}, bp1 = (v2f){0,0}, bp2 = (v2f){0,0};
#pragma unroll
        for (int q = 0; q < 4; ++q) {
            int k = k0 + q;
            v2f hb2; hb2.x = fast_tanh(ab[q].x + bbv[q]); hb2.y = fast_tanh(ab[q].y + bbv[q]);
            bp0 += hb2 * BW2[k * 3 + 0];
            bp1 += hb2 * BW2[k * 3 + 1];
            bp2 += hb2 * BW2[k * 3 + 2];
        }
        bp0 = red64(bp0); bp1 = red64(bp1); bp2 = red64(bp2);
        if (c == 0) {
            red2[s0][0] = bp0.x; red2[s0 + 1][0] = bp0.y;
            red2[s0][1] = bp1.x; red2[s0 + 1][1] = bp1.y;
            red2[s0][2] = bp2.x; red2[s0 + 1][2] = bp2.y;
        }
    }
    __syncthreads();

    // ---------------- GEMM1: Y1[n][j] = sum_k LW2[k][n] * X1[j][k] ----------------
    // X1 columns j = f*16 + s: f=0 -> h1, f=1..3 -> t1*w1d_f. K halved for LDS.
    v4f acc[2][4], alo[2][4];
#pragma unroll
    for (int m = 0; m < 2; ++m)
#pragma unroll
        for (int b = 0; b < 4; ++b) { acc[m][b] = (v4f){0,0,0,0}; alo[m][b] = (v4f){0,0,0,0}; }

    for (int half = 0; half < 2; ++half) {
        // ---- build X1 planes for this K-half: thread (j=c, run=r) covers 16 k ----
        {
            int s = c & 15, f = c >> 4;
            int kb = half * 128 + r * 16;
            float vv[16];
#pragma unroll
            for (int qq = 0; qq < 4; ++qq) {
                v4f h4 = *(const v4f*)&h1L[s * 260 + kb + qq * 4];
                if (f == 0) {
#pragma unroll
                    for (int e = 0; e < 4; ++e) vv[qq * 4 + e] = h4[e];
                } else {
                    v4f wq = *(const v4f*)(LW1 + (f - 1) * HID + kb + qq * 4);
#pragma unroll
                    for (int e = 0; e < 4; ++e) vv[qq * 4 + e] = (1.0f - h4[e] * h4[e]) * wq[e];
                }
            }
            unsigned short sp[3][16];
#pragma unroll
            for (int e = 0; e < 16; ++e) split3(vv[e], sp[0][e], sp[1][e], sp[2][e]);
#pragma unroll
            for (int p = 0; p < 3; ++p)
#pragma unroll
                for (int bh = 0; bh < 2; ++bh) {
                    i32x4 pk;
#pragma unroll
                    for (int d = 0; d < 4; ++d)
                        pk[d] = (int)sp[p][bh * 8 + 2 * d] | ((int)sp[p][bh * 8 + 2 * d + 1] << 16);
                    *(i32x4*)(ldsX + x1_off(p, c, r * 2 + bh)) = pk;
                }
        }
        __syncthreads();
        // ---- 4 K-steps: 6-product Ozaki (hh via hazard-safe zero-C MFMA) ----
        for (int ksl = 0; ksl < 4; ++ksl) {
            int ksg = half * 4 + ksl;
            int kb16 = ksl * 4 + lq;
            const unsigned short* a0 = PL + mt0 * 4096 + ksg * 512 + c * 8;
            i32x4 Ah[2], Am[2], Al[2];
#pragma unroll
            for (int m = 0; m < 2; ++m) {
                Ah[m] = *(const i32x4*)(a0 + m * 4096);
                Am[m] = *(const i32x4*)(a0 + 65536 + m * 4096);
                Al[m] = *(const i32x4*)(a0 + 131072 + m * 4096);
            }
            // plane 0 (Bh): hh -> safe fold; mh, lh -> alo
#pragma unroll
            for (int b = 0; b < 4; ++b) {
                i32x4 B = *(const i32x4*)(ldsX + x1_off(0, b * 16 + l15, kb16));
                acc[0][b] += mfma_safe(Ah[0], B);
                acc[1][b] += mfma_safe(Ah[1], B);
                mfma_acc(alo[0][b], Am[0], B); mfma_acc(alo[1][b], Am[1], B);
                mfma_acc(alo[0][b], Al[0], B); mfma_acc(alo[1][b], Al[1], B);
            }
            // plane 1 (Bm): hm, mm -> alo   (lm dropped: ~2^-24, residual class)
#pragma unroll
            for (int b = 0; b < 4; ++b) {
                i32x4 B = *(const i32x4*)(ldsX + x1_off(1, b * 16 + l15, kb16));
                mfma_acc(alo[0][b], Ah[0], B); mfma_acc(alo[1][b], Ah[1], B);
                mfma_acc(alo[0][b], Am[0], B); mfma_acc(alo[1][b], Am[1], B);
            }
            // plane 2 (Bl): hl -> alo       (ml dropped: ~2^-24, residual class)
#pragma unroll
            for (int b = 0; b < 4; ++b) {
                i32x4 B = *(const i32x4*)(ldsX + x1_off(2, b * 16 + l15, kb16));
                mfma_acc(alo[0][b], Ah[0], B); mfma_acc(alo[1][b], Ah[1], B);
            }
        }
        __syncthreads();
    }
    mfma_read_fence();
#pragma unroll
    for (int m = 0; m < 2; ++m)
#pragma unroll
        for (int b = 0; b < 4; ++b) acc[m][b] += alo[m][b];

    // ---------------- epilogue 1: H quad part, X2 = {g2 rows 0-15, pd rows 16-31} ----------------
    // Lane holds all 4 families for (n = mt*16+lq*4+i, sample = l15): shuffle-free.
    float Hp[6] = {0, 0, 0, 0, 0, 0};
    const int sE = l15;
    const float td0s = xs2[0][sE], td1s = xs2[1][sE], td2s = xs2[2][sE];
#pragma unroll
    for (int m = 0; m < 2; ++m) {
        int nq = (mt0 + m) * 16 + lq * 4;
        v4f b2 = *(const v4f*)(Lb2 + nq);
        v4f w3 = *(const v4f*)(LW3 + nq);
        unsigned short sg[3][4], sd[3][4];
#pragma unroll
        for (int i = 0; i < 4; ++i) {
            float a2 = acc[m][0][i] + b2[i];
            float P0 = acc[m][1][i], P1 = acc[m][2][i], P2 = acc[m][3][i];
            float h2 = fast_tanh(a2);
            float t2 = 1.0f - h2 * h2;
            float g2 = t2 * w3[i];
            float m2 = -2.0f * h2 * g2;
            Hp[0] += m2 * P0 * P0; Hp[1] += m2 * P0 * P1; Hp[2] += m2 * P1 * P1;
            Hp[3] += m2 * P0 * P2; Hp[4] += m2 * P1 * P2; Hp[5] += m2 * P2 * P2;
            float pd = m2 * (P0 * td0s + P1 * td1s + P2 * td2s);
            split3(g2, sg[0][i], sg[1][i], sg[2][i]);
            split3(pd, sd[0][i], sd[1][i], sd[2][i]);
        }
        int kb16 = (mt0 + m) * 2 + (lq >> 1);
        int off8 = (lq & 1) * 8;
#pragma unroll
        for (int p = 0; p < 3; ++p) {
            i32x2 a, bpk;
            a[0]   = (int)sg[p][0] | ((int)sg[p][1] << 16);
            a[1]   = (int)sg[p][2] | ((int)sg[p][3] << 16);
            bpk[0] = (int)sd[p][0] | ((int)sd[p][1] << 16);
            bpk[1] = (int)sd[p][2] | ((int)sd[p][3] << 16);
            *(i32x2*)(ldsX + x2_off(p, sE, kb16) + off8)      = a;
            *(i32x2*)(ldsX + x2_off(p, 16 + sE, kb16) + off8) = bpk;
        }
    }
#pragma unroll
    for (int j = 0; j < 6; ++j) {
        float v = red_lq(Hp[j]);
        if (lq == 0) redM[r][sE][j] = v;
    }
    __syncthreads();

    // ---------------- GEMM2: Y2[k][j2] = sum_n LW2[k][n] * X2[j2][n] (6-product) ----------------
    v4f acc2[2][2], alo2[2][2];
#pragma unroll
    for (int m = 0; m < 2; ++m)
#pragma unroll
        for (int b = 0; b < 2; ++b) { acc2[m][b] = (v4f){0,0,0,0}; alo2[m][b] = (v4f){0,0,0,0}; }

    for (int ks = 0; ks < 8; ++ks) {
        int kb16 = ks * 4 + lq;
        const unsigned short* a0 = PL + 196608 + mt0 * 4096 + ks * 512 + c * 8;
        i32x4 Ah[2], Am[2], Al[2];
#pragma unroll
        for (int m = 0; m < 2; ++m) {
            Ah[m] = *(const i32x4*)(a0 + m * 4096);
            Am[m] = *(const i32x4*)(a0 + 65536 + m * 4096);
            Al[m] = *(const i32x4*)(a0 + 131072 + m * 4096);
        }
        // plane 0 (Bh): hh -> safe fold; mh, lh -> alo
#pragma unroll
        for (int b = 0; b < 2; ++b) {
            i32x4 B = *(const i32x4*)(ldsX + x2_off(0, b * 16 + l15, kb16));
            acc2[0][b] += mfma_safe(Ah[0], B);
            acc2[1][b] += mfma_safe(Ah[1], B);
            mfma_acc(alo2[0][b], Am[0], B); mfma_acc(alo2[1][b], Am[1], B);
            mfma_acc(alo2[0][b], Al[0], B); mfma_acc(alo2[1][b], Al[1], B);
        }
        // plane 1 (Bm): hm, mm -> alo   (lm dropped)
#pragma unroll
        for (int b = 0; b < 2; ++b) {
            i32x4 B = *(const i32x4*)(ldsX + x2_off(1, b * 16 + l15, kb16));
            mfma_acc(alo2[0][b], Ah[0], B); mfma_acc(alo2[1][b], Ah[1], B);
            mfma_acc(alo2[0][b], Am[0], B); mfma_acc(alo2[1][b], Am[1], B);
        }
        // plane 2 (Bl): hl -> alo       (ml dropped)
#pragma unroll
        for (int b = 0; b < 2; ++b) {
            i32x4 B = *(const i32x4*)(ldsX + x2_off(2, b * 16 + l15, kb16));
            mfma_acc(alo2[0][b], Ah[0], B); mfma_acc(alo2[1][b], Ah[1], B);
        }
    }
    mfma_read_fence();
#pragma unroll
    for (int m = 0; m < 2; ++m)
#pragma unroll
        for (int b = 0; b < 2; ++b) acc2[m][b] += alo2[m][b];

    // ---------------- epilogue 2: dL, C*td, H diag part (shuffle-free) ----------------
    {
        v4f dl0 = (v4f){0,0,0,0}, dl1 = dl0, dl2 = dl0;
        v4f ct0 = dl0, ct1 = dl0, ct2 = dl0;
        v4f hd[6];
#pragma unroll
        for (int j = 0; j < 6; ++j) hd[j] = (v4f){0,0,0,0};
#pragma unroll
        for (int m = 0; m < 2; ++m) {
            int kq = (mt0 + m) * 16 + lq * 4;
            v4f U = acc2[m][0];
            v4f W = acc2[m][1];
            v4f h1 = *(const v4f*)&h1L[sE * 260 + kq];
            v4f wd0 = *(const v4f*)(LW1 + 0 * HID + kq);
            v4f wd1 = *(const v4f*)(LW1 + 1 * HID + kq);
            v4f wd2 = *(const v4f*)(LW1 + 2 * HID + kq);
            v4f wt0 = *(const v4f*)(LW1 + 6 * HID + kq);
            v4f wt1 = *(const v4f*)(LW1 + 7 * HID + kq);
            v4f wt2 = *(const v4f*)(LW1 + 8 * HID + kq);
            v4f t1 = 1.0f - h1 * h1;
            v4f g1 = U * t1;
            dl0 += g1 * wt0; dl1 += g1 * wt1; dl2 += g1 * wt2;
            v4f cf = -2.0f * U * h1 * t1;
            v4f wdtd = td0s * wd0 + td1s * wd1 + td2s * wd2;
            v4f ct = t1 * W + cf * wdtd;
            ct0 += ct * wt0; ct1 += ct * wt1; ct2 += ct * wt2;
            hd[0] += cf * wd0 * wd0; hd[1] += cf * wd0 * wd1; hd[2] += cf * wd1 * wd1;
            hd[3] += cf * wd0 * wd2; hd[4] += cf * wd1 * wd2; hd[5] += cf * wd2 * wd2;
        }
        float vals[12];
        vals[0] = hsum4(dl0); vals[1] = hsum4(dl1); vals[2] = hsum4(dl2);
        vals[3] = hsum4(ct0); vals[4] = hsum4(ct1); vals[5] = hsum4(ct2);
#pragma unroll
        for (int j = 0; j < 6; ++j) vals[6 + j] = hsum4(hd[j]);
#pragma unroll
        for (int j = 0; j < 12; ++j) {
            float v = red_lq(vals[j]);
            if (lq == 0) redM[r][sE][6 + j] = v;
        }
    }
    __syncthreads();

    // ---------------- per-sample 3x3 symmetric solve (fp64) ----------------
    if (tid < SB) {
        int s = tid;
        int gs = sg0 + s;
        double Ha = 0, Hb = 0, Hd = 0, Hc = 0, He = 0, Hf = 0;
        double dL0 = 0, dL1 = 0, dL2 = 0, ct0 = 0, ct1 = 0, ct2 = 0;
#pragma unroll
        for (int w = 0; w < 8; ++w) {
            Ha += (double)redM[w][s][0] + (double)redM[w][s][12];
            Hb += (double)redM[w][s][1] + (double)redM[w][s][13];
            Hd += (double)redM[w][s][2] + (double)redM[w][s][14];
            Hc += (double)redM[w][s][3] + (double)redM[w][s][15];
            He += (double)redM[w][s][4] + (double)redM[w][s][16];
            Hf += (double)redM[w][s][5] + (double)redM[w][s][17];
            dL0 += redM[w][s][6]; dL1 += redM[w][s][7]; dL2 += redM[w][s][8];
            ct0 += redM[w][s][9]; ct1 += redM[w][s][10]; ct2 += redM[w][s][11];
        }
        double rhs[3];
        rhs[0] = (double)g_tau[gs * 3 + 0] + (double)red2[s][0] + (double)Bb2[0] + dL0 - ct0;
        rhs[1] = (double)g_tau[gs * 3 + 1] + (double)red2[s][1] + (double)Bb2[1] + dL1 - ct1;
        rhs[2] = (double)g_tau[gs * 3 + 2] + (double)red2[s][2] + (double)Bb2[2] + dL2 - ct2;
        double I00 = Hd * Hf - He * He;
        double I01 = Hc * He - Hb * Hf;
        double I02 = Hb * He - Hc * Hd;
        double I11 = Ha * Hf - Hc * Hc;
        double I12 = Hb * Hc - Ha * He;
        double I22 = Ha * Hd - Hb * Hb;
        double det = Ha * I00 + Hb * I01 + Hc * I02;
        double inv = 1.0 / det;
        out[gs * 3 + 0] = (float)((I00 * rhs[0] + I01 * rhs[1] + I02 * rhs[2]) * inv);
        out[gs * 3 + 1] = (float)((I01 * rhs[0] + I11 * rhs[1] + I12 * rhs[2]) * inv);
        out[gs * 3 + 2] = (float)((I02 * rhs[0] + I12 * rhs[1] + I22 * rhs[2]) * inv);
    }
}

// ============================================================================
// fallback path (Round-3 VALU kernel, used only if ws_size too small)
// ============================================================================
__global__ void transpose256(const float* __restrict__ in, float* __restrict__ outT) {
    __shared__ float tile[32][33];
    const int tid = threadIdx.x;
    const int bx = blockIdx.x & 7;
    const int by = blockIdx.x >> 3;
    const int tx = tid & 31, ty = tid >> 5;
#pragma unroll
    for (int yy = ty; yy < 32; yy += 8)
        tile[yy][tx] = in[(by * 32 + yy) * HID + bx * 32 + tx];
    __syncthreads();
#pragma unroll
    for (int yy = ty; yy < 32; yy += 8)
        outT[(bx * 32 + yy) * HID + by * 32 + tx] = tile[tx][yy];
}

__device__ __forceinline__ v2f pk_mul_lo(v2f a, v2f b) {
    v2f d;
    asm("v_pk_mul_f32 %0, %1, %2 op_sel_hi:[1,0]" : "=v"(d) : "v"(a), "v"(b));
    return d;
}
__device__ __forceinline__ v2f pk_mul_hi(v2f a, v2f b) {
    v2f d;
    asm("v_pk_mul_f32 %0, %1, %2 op_sel:[0,1] op_sel_hi:[1,1]" : "=v"(d) : "v"(a), "v"(b));
    return d;
}

__launch_bounds__(256, 4)
__global__ void lnn_valu(
    const float* __restrict__ g_td, const float* __restrict__ g_sd,
    const float* __restrict__ g_th, const float* __restrict__ g_z,
    const float* __restrict__ g_s,  const float* __restrict__ g_sdd,
    const float* __restrict__ g_tau,
    const float* __restrict__ LW1, const float* __restrict__ Lb1,
    const float* __restrict__ LW2, const float* __restrict__ Lb2,
    const float* __restrict__ LW3,
    const float* __restrict__ BW1, const float* __restrict__ Bb1,
    const float* __restrict__ BW2, const float* __restrict__ Bb2,
    const float* __restrict__ W2T,
    float* __restrict__ out)
{
    __shared__ __align__(16) float ldsP[HID * 32];
    __shared__ __align__(16) float xs2[16][8];
    __shared__ __align__(16) float red[8][16];

    const int tid = threadIdx.x;
    const int c   = tid & 63;
    const int r   = tid >> 6;
    const int k0  = c * 4;
    const int s0  = r * 2;
    const int sg0 = blockIdx.x * 8;
    const int o1  = r * 8;
    const int o2  = r * 4;
    const int sw1 = (c & 3) << 3;
    const int sw2 = (c & 3) << 2;

    if (tid < 24) {
        int s = tid / 3, m = tid - s * 3;
        xs2[m][s]      = g_td [(sg0 + s) * 3 + m];
        xs2[3 + m][s]  = g_sd [(sg0 + s) * 3 + m];
        xs2[6 + m][s]  = g_th [(sg0 + s) * 3 + m];
        xs2[10 + m][s] = g_s  [(sg0 + s) * 3 + m];
        xs2[13 + m][s] = g_sdd[(sg0 + s) * 3 + m];
    } else if (tid < 32) {
        int s = tid - 24;
        xs2[9][s] = g_z[sg0 + s];
    }
    __syncthreads();

    float h1r[2][4];
    {
        v2f a1[4];
#pragma unroll
        for (int q = 0; q < 4; ++q) a1[q] = (v2f){0.0f, 0.0f};
#pragma unroll
        for (int m = 0; m < 10; ++m) {
            v4f w4 = *(const v4f*)(LW1 + m * HID + k0);
            v2f wlo = __builtin_shufflevector(w4, w4, 0, 1);
            v2f whi = __builtin_shufflevector(w4, w4, 2, 3);
            v2f xmv = *(const v2f*)&xs2[m][s0];
            ACC4(a1, xmv);
        }
        v4f bb  = *(const v4f*)(Lb1 + k0);
        v4f wd0 = *(const v4f*)(LW1 + 0 * HID + k0);
        v4f wd1 = *(const v4f*)(LW1 + 1 * HID + k0);
        v4f wd2 = *(const v4f*)(LW1 + 2 * HID + k0);
#pragma unroll
        for (int q = 0; q < 4; ++q) {
            float hx = fast_tanh(a1[q].x + bb[q]);
            float hy = fast_tanh(a1[q].y + bb[q]);
            h1r[0][q] = hx; h1r[1][q] = hy;
            float tx = 1.0f - hx * hx, ty = 1.0f - hy * hy;
            int rb = (k0 + q) * 32 + (o1 ^ sw1);
            *(v4f*)&ldsP[rb]     = (v4f){ hx, hy, tx * wd0[q], ty * wd0[q] };
            *(v4f*)&ldsP[rb + 4] = (v4f){ tx * wd1[q], ty * wd1[q], tx * wd2[q], ty * wd2[q] };
        }
    }

    {
        v2f ab[4];
#pragma unroll
        for (int q = 0; q < 4; ++q) ab[q] = (v2f){0.0f, 0.0f};
#pragma unroll
        for (int m = 0; m < 9; ++m) {
            v4f w4 = *(const v4f*)(BW1 + m * HID + k0);
            v2f wlo = __builtin_shufflevector(w4, w4, 0, 1);
            v2f whi = __builtin_shufflevector(w4, w4, 2, 3);
            int xi = (m < 3) ? (6 + m) : (7 + m);
            v2f xmv = *(const v2f*)&xs2[xi][s0];
            ACC4(ab, xmv);
        }
        v4f bbv = *(const v4f*)(Bb1 + k0);
        v2f bp0 = (v2f){0,0}, bp1 = (v2f){0,0}, bp2 = (v2f){0,0};
#pragma unroll
        for (int q = 0; q < 4; ++q) {
            int k = k0 + q;
            v2f hb; hb.x = fast_tanh(ab[q].x + bbv[q]); hb.y = fast_tanh(ab[q].y + bbv[q]);
            bp0 += hb * BW2[k * 3 + 0];
            bp1 += hb * BW2[k * 3 + 1];
            bp2 += hb * BW2[k * 3 + 2];
        }
        bp0 = red64(bp0); bp1 = red64(bp1); bp2 = red64(bp2);
        if (c == 0) {
            red[s0][12] = bp0.x; red[s0 + 1][12] = bp0.y;
            red[s0][13] = bp1.x; red[s0 + 1][13] = bp1.y;
            red[s0][14] = bp2.x; red[s0 + 1][14] = bp2.y;
        }
    }
    __syncthreads();

    v2f acc[4][4];
#pragma unroll
    for (int f = 0; f < 4; ++f)
#pragma unroll
        for (int q = 0; q < 4; ++q) acc[f][q] = (v2f){0.0f, 0.0f};

    for (int n0 = 0; n0 < HID; n0 += 4) {
        const float* prow = &ldsP[n0 * 32 + (o1 ^ (((n0 >> 2) & 3) << 3))];
        const float* wrow = LW2 + n0 * HID + k0;
#pragma unroll
        for (int j = 0; j < 4; ++j) {
            v4f pA = *(const v4f*)(prow + j * 32);
            v4f pB = *(const v4f*)(prow + j * 32 + 4);
            v4f w4 = *(const v4f*)(wrow + j * HID);
            v2f wlo = __builtin_shufflevector(w4, w4, 0, 1);
            v2f whi = __builtin_shufflevector(w4, w4, 2, 3);
            v2f hv = __builtin_shufflevector(pA, pA, 0, 1);
            v2f i1 = __builtin_shufflevector(pA, pA, 2, 3);
            v2f i2 = __builtin_shufflevector(pB, pB, 0, 1);
            v2f i3 = __builtin_shufflevector(pB, pB, 2, 3);
            ACC4(acc[0], hv);
            ACC4(acc[1], i1);
            ACC4(acc[2], i2);
            ACC4(acc[3], i3);
        }
    }
    __syncthreads();

    v2f Hp[6];
#pragma unroll
    for (int i = 0; i < 6; ++i) Hp[i] = (v2f){0.0f, 0.0f};
    const v2f td0v = *(const v2f*)&xs2[0][s0];
    const v2f td1v = *(const v2f*)&xs2[1][s0];
    const v2f td2v = *(const v2f*)&xs2[2][s0];
    {
        v4f b2v = *(const v4f*)(Lb2 + k0);
        v4f w3v = *(const v4f*)(LW3 + k0);
#pragma unroll
        for (int q = 0; q < 4; ++q) {
            v2f a2 = acc[0][q] + b2v[q];
            v2f h2; h2.x = fast_tanh(a2.x); h2.y = fast_tanh(a2.y);
            v2f t2 = 1.0f - h2 * h2;
            v2f g2 = t2 * w3v[q];
            v2f m2 = -2.0f * h2 * g2;
            v2f P0 = acc[1][q], P1 = acc[2][q], P2 = acc[3][q];
            v2f m2P0 = m2 * P0, m2P1 = m2 * P1;
            Hp[0] += m2P0 * P0;
            Hp[1] += m2P0 * P1;
            Hp[2] += m2P1 * P1;
            Hp[3] += m2P0 * P2;
            Hp[4] += m2P1 * P2;
            Hp[5] += m2 * P2 * P2;
            v2f ptd = td0v * P0 + td1v * P1 + td2v * P2;
            v2f pd  = m2 * ptd;
            *(v4f*)&ldsP[(k0 + q) * 32 + (o2 ^ sw2)] = (v4f){ g2.x, g2.y, pd.x, pd.y };
        }
    }
    __syncthreads();

#pragma unroll
    for (int f = 0; f < 2; ++f)
#pragma unroll
        for (int q = 0; q < 4; ++q) acc[f][q] = (v2f){0.0f, 0.0f};

    for (int n0 = 0; n0 < HID; n0 += 4) {
        const float* prow = &ldsP[n0 * 32 + (o2 ^ (((n0 >> 2) & 3) << 2))];
        const float* wrow = W2T + n0 * HID + k0;
#pragma unroll
        for (int j = 0; j < 4; ++j) {
            v4f p  = *(const v4f*)(prow + j * 32);
            v4f w4 = *(const v4f*)(wrow + j * HID);
            v2f wlo = __builtin_shufflevector(w4, w4, 0, 1);
            v2f whi = __builtin_shufflevector(w4, w4, 2, 3);
            v2f g2v = __builtin_shufflevector(p, p, 0, 1);
            v2f pdv = __builtin_shufflevector(p, p, 2, 3);
            ACC4(acc[0], g2v);
            ACC4(acc[1], pdv);
        }
    }

    v2f dLp[3], ctp[3];
#pragma unroll
    for (int i = 0; i < 3; ++i) { dLp[i] = (v2f){0,0}; ctp[i] = (v2f){0,0}; }
    {
        v4f wd0 = *(const v4f*)(LW1 + 0 * HID + k0);
        v4f wd1 = *(const v4f*)(LW1 + 1 * HID + k0);
        v4f wd2 = *(const v4f*)(LW1 + 2 * HID + k0);
        v4f wt0 = *(const v4f*)(LW1 + 6 * HID + k0);
        v4f wt1 = *(const v4f*)(LW1 + 7 * HID + k0);
        v4f wt2 = *(const v4f*)(LW1 + 8 * HID + k0);
#pragma unroll
        for (int q = 0; q < 4; ++q) {
            v2f h1; h1.x = h1r[0][q]; h1.y = h1r[1][q];
            v2f t1 = 1.0f - h1 * h1;
            v2f u  = acc[0][q];
            v2f w  = acc[1][q];
            v2f g1 = u * t1;
            dLp[0] += g1 * wt0[q]; dLp[1] += g1 * wt1[q]; dLp[2] += g1 * wt2[q];
            v2f cf = -2.0f * u * h1 * t1;
            v2f wdtd = td0v * wd0[q] + td1v * wd1[q] + td2v * wd2[q];
            v2f ct = t1 * w + cf * wdtd;
            ctp[0] += ct * wt0[q]; ctp[1] += ct * wt1[q]; ctp[2] += ct * wt2[q];
            float w00 = wd0[q] * wd0[q], w01 = wd0[q] * wd1[q], w11 = wd1[q] * wd1[q];
            float w02 = wd0[q] * wd2[q], w12 = wd1[q] * wd2[q], w22 = wd2[q] * wd2[q];
            Hp[0] += cf * w00; Hp[1] += cf * w01; Hp[2] += cf * w11;
            Hp[3] += cf * w02; Hp[4] += cf * w12; Hp[5] += cf * w22;
        }
    }

#pragma unroll
    for (int i = 0; i < 6; ++i) {
        v2f v = red64(Hp[i]);
        if (c == 0) { red[s0][i] = v.x; red[s0 + 1][i] = v.y; }
    }
#pragma unroll
    for (int i = 0; i < 3; ++i) {
        v2f v = red64(dLp[i]);
        if (c == 0) { red[s0][6 + i] = v.x; red[s0 + 1][6 + i] = v.y; }
    }
#pragma unroll
    for (int i = 0; i < 3; ++i) {
        v2f v = red64(ctp[i]);
        if (c == 0) { red[s0][9 + i] = v.x; red[s0 + 1][9 + i] = v.y; }
    }
    __syncthreads();

    if (tid < 8) {
        int s = tid;
        int gs = sg0 + s;
        double Ha = red[s][0], Hb = red[s][1], Hd = red[s][2];
        double Hc = red[s][3], He = red[s][4], Hf = red[s][5];
        double rhs[3];
#pragma unroll
        for (int i = 0; i < 3; ++i) {
            rhs[i] = (double)g_tau[gs * 3 + i] + (double)red[s][12 + i] + (double)Bb2[i]
                   + (double)red[s][6 + i]
                   - (double)red[s][9 + i];
        }
        double I00 = Hd * Hf - He * He;
        double I01 = Hc * He - Hb * Hf;
        double I02 = Hb * He - Hc * Hd;
        double I11 = Ha * Hf - Hc * Hc;
        double I12 = Hb * Hc - Ha * He;
        double I22 = Ha * Hd - Hb * Hb;
        double det = Ha * I00 + Hb * I01 + Hc * I02;
        double inv = 1.0 / det;
        out[gs * 3 + 0] = (float)((I00 * rhs[0] + I01 * rhs[1] + I02 * rhs[2]) * inv);
        out[gs * 3 + 1] = (float)((I01 * rhs[0] + I11 * rhs[1] + I12 * rhs[2]) * inv);
        out[gs * 3 + 2] = (float)((I02 * rhs[0] + I12 * rhs[1] + I22 * rhs[2]) * inv);
    }
}

extern "C" void kernel_launch(void* const* d_in, const int* in_sizes, int n_in,
                              void* d_out, int out_size, void* d_ws, size_t ws_size,
                              hipStream_t stream) {
    const float* td  = (const float*)d_in[0];
    const float* sd  = (const float*)d_in[1];
    const float* th  = (const float*)d_in[2];
    const float* z   = (const float*)d_in[3];
    const float* s_  = (const float*)d_in[4];
    const float* sdd = (const float*)d_in[5];
    const float* tau = (const float*)d_in[6];
    const float* LW1 = (const float*)d_in[7];
    const float* Lb1 = (const float*)d_in[8];
    const float* LW2 = (const float*)d_in[9];
    const float* Lb2 = (const float*)d_in[10];
    const float* LW3 = (const float*)d_in[11];
    // d_in[12] = Lb3 (constant bias: no effect on derivatives)
    const float* BW1 = (const float*)d_in[13];
    const float* Bb1 = (const float*)d_in[14];
    const float* BW2 = (const float*)d_in[15];
    const float* Bb2 = (const float*)d_in[16];
    float* outp = (float*)d_out;

    const int Btot = in_sizes[0] / 3;

    if (ws_size >= 6u * 65536u * 2u) {
        unsigned short* planes = (unsigned short*)d_ws;   // 6 x 128KB bf16 planes
        build_planes<<<dim3(64), dim3(256), 0, stream>>>(LW2, planes);
        const int nblk = Btot / SB;
        lnn_mfma<<<dim3(nblk), dim3(512), 0, stream>>>(
            td, sd, th, z, s_, sdd, tau, LW1, Lb1, Lb2, LW3,
            BW1, Bb1, BW2, Bb2, planes, outp);
    } else {
        float* W2T = (float*)d_ws;
        transpose256<<<dim3(64), dim3(256), 0, stream>>>(LW2, W2T);
        const int nblk = Btot / 8;
        lnn_valu<<<dim3(nblk), dim3(256), 0, stream>>>(
            td, sd, th, z, s_, sdd, tau, LW1, Lb1, LW2, Lb2, LW3,
            BW1, Bb1, BW2, Bb2, W2T, outp);
    }
}